// Round 8
// baseline (282.585 us; speedup 1.0000x reference)
//
#include <hip/hip_runtime.h>
#include <hip/hip_bf16.h>

#define NEGS 0.01f
#define BNEPS 1e-5f

typedef short bf16x8 __attribute__((ext_vector_type(8)));
typedef float f32x4 __attribute__((ext_vector_type(4)));

// split fp32 -> hi/lo bf16 (RNE via HW cvt), v ~= hi + lo, rel err ~2^-18
__device__ __forceinline__ void split2(float v, short& hi, short& lo) {
    __hip_bfloat16 bh = __float2bfloat16(v);
    unsigned short hu = __builtin_bit_cast(unsigned short, bh);
    hi = (short)hu;
    float hf = __uint_as_float(((unsigned)hu) << 16);
    __hip_bfloat16 bl = __float2bfloat16(v - hf);
    lo = (short)__builtin_bit_cast(unsigned short, bl);
}

// ---------------------------------------------------------------------------
// Precompute: split weight matrices into hi/lo bf16, TRANSPOSED to [N][K32].
// ---------------------------------------------------------------------------
__global__ __launch_bounds__(256) void split_all(
    const float* __restrict__ W1, const float* __restrict__ W2,
    const float* __restrict__ W3, const float* __restrict__ L1,
    short* __restrict__ h1, short* __restrict__ l1,
    short* __restrict__ h2, short* __restrict__ l2,
    short* __restrict__ h3, short* __restrict__ l3,
    short* __restrict__ h4, short* __restrict__ l4)
{
    int idx = blockIdx.x * 256 + threadIdx.x;
    const float* B; short *H, *L; int K, N, K32, loc;
    if (idx < 20480)      { B = W1; H = h1; L = l1; K = 133; N = 128;  K32 = 160; loc = idx; }
    else if (idx < 36864) { B = W2; H = h2; L = l2; K = 128; N = 128;  K32 = 128; loc = idx - 20480; }
    else if (idx < 53248) { B = W3; H = h3; L = l3; K = 128; N = 128;  K32 = 128; loc = idx - 36864; }
    else                  { B = L1; H = h4; L = l4; K = 256; N = 1024; K32 = 256; loc = idx - 53248; }
    int n = loc % N, k = loc / N;
    float v = (k < K) ? B[(long)k * N + n] : 0.f;
    short hi, lo; split2(v, hi, lo);
    H[(long)n * K32 + k] = hi;
    L[(long)n * K32 + k] = lo;
}

// ---------------------------------------------------------------------------
// B-resident bf16-split MFMA GEMM. Only B-HI staged to LDS (43KB for K32=160
// -> 3 blocks/CU); B-LO fragments read direct from global (L2-resident).
// Barrier-free K-loop, A global->regs, split in-reg, 3-term MFMA (hh+hl+lh).
// Block = 128x128, 4 waves x 32 rows. EPI 1: bias+lrelu+BN (MLP head).
// ---------------------------------------------------------------------------
template<int K, int K32, int EPI>
__global__ __launch_bounds__(256) void gemm_bres(
    const float* __restrict__ A, const short* __restrict__ Bh_t,
    const short* __restrict__ Bl_t, float* __restrict__ C, int N,
    const float* __restrict__ bias, const float* __restrict__ bng,
    const float* __restrict__ bnb, const float* __restrict__ bnrm,
    const float* __restrict__ bnrv)
{
    constexpr int KP = K32 + 8;
    constexpr int NKS = K32 / 32;
    __shared__ short Bhs[128 * KP];

    const int tid = threadIdx.x;
    const int bm = blockIdx.x * 128, n0 = blockIdx.y * 128;
    const int lane = tid & 63, w = tid >> 6;
    const int lm = lane & 15, lk = (lane >> 4) * 8;

    for (int i = tid; i < 128 * (K32 / 8); i += 256) {
        int n = i / (K32 / 8), kb = (i % (K32 / 8)) * 8;
        *(bf16x8*)&Bhs[n * KP + kb] = *(const bf16x8*)&Bh_t[(long)(n0 + n) * K32 + kb];
    }
    __syncthreads();

    const f32x4 zz = {0.f, 0.f, 0.f, 0.f};
    f32x4 acc[2][8];
#pragma unroll
    for (int i = 0; i < 2; ++i)
#pragma unroll
        for (int j = 0; j < 8; ++j) acc[i][j] = zz;

    const int r0 = bm + w * 32;
    for (int ks = 0; ks < NKS; ++ks) {
        const int k0 = ks * 32 + lk;
        bf16x8 ah[2], al[2];
#pragma unroll
        for (int mt = 0; mt < 2; ++mt) {
            const long rowb = (long)(r0 + mt * 16 + lm) * K;
            float av[8];
            if constexpr (K % 4 == 0) {
                const float4 v0 = *(const float4*)&A[rowb + k0];
                const float4 v1 = *(const float4*)&A[rowb + k0 + 4];
                av[0] = v0.x; av[1] = v0.y; av[2] = v0.z; av[3] = v0.w;
                av[4] = v1.x; av[5] = v1.y; av[6] = v1.z; av[7] = v1.w;
            } else {
#pragma unroll
                for (int j = 0; j < 8; ++j) {
                    int kk = k0 + j;
                    av[j] = (kk < K) ? A[rowb + kk] : 0.f;
                }
            }
#pragma unroll
            for (int j = 0; j < 8; ++j) {
                short h_, l_; split2(av[j], h_, l_);
                ah[mt][j] = h_; al[mt][j] = l_;
            }
        }
#pragma unroll
        for (int nt = 0; nt < 8; ++nt) {
            bf16x8 bh = *(const bf16x8*)&Bhs[(nt * 16 + lm) * KP + k0];
            bf16x8 bl = *(const bf16x8*)&Bl_t[(long)(n0 + nt * 16 + lm) * K32 + k0];
#pragma unroll
            for (int mt = 0; mt < 2; ++mt) {
                acc[mt][nt] = __builtin_amdgcn_mfma_f32_16x16x32_bf16(ah[mt], bh, acc[mt][nt], 0, 0, 0);
                acc[mt][nt] = __builtin_amdgcn_mfma_f32_16x16x32_bf16(ah[mt], bl, acc[mt][nt], 0, 0, 0);
                acc[mt][nt] = __builtin_amdgcn_mfma_f32_16x16x32_bf16(al[mt], bh, acc[mt][nt], 0, 0, 0);
            }
        }
    }

#pragma unroll
    for (int mt = 0; mt < 2; ++mt) {
        const int row0 = r0 + mt * 16 + (lane >> 4) * 4;
#pragma unroll
        for (int nt = 0; nt < 8; ++nt) {
            const int col = n0 + nt * 16 + lm;
            float bi = 0.f, sc_ = 1.f, rm_ = 0.f, bb_ = 0.f;
            if constexpr (EPI == 1) {
                bi = bias[col];
                sc_ = (1.0f / sqrtf(bnrv[col] + BNEPS)) * bng[col];
                rm_ = bnrm[col]; bb_ = bnb[col];
            }
#pragma unroll
            for (int r = 0; r < 4; ++r) {
                float v = acc[mt][nt][r];
                if constexpr (EPI == 1) {
                    v += bi;
                    v = v >= 0.f ? v : NEGS * v;
                    v = (v - rm_) * sc_ + bb_;
                }
                C[(long)(row0 + r) * N + col] = v;
            }
        }
    }
}

// ---------------------------------------------------------------------------
// Fused per-graph: GCN finish (CSR, atomic-free float4 gather-agg, act in
// LDS) + TopK (wave0 sort) + in-place packed-edge remap + FUSED NEXT-LAYER
// GEMM via MFMA (A = gated pooled rows from LDS, W hi/lo from L2) + readout.
// h_s stride 132 (aligned, ~2-way-conflict MFMA A-reads). MT = m-tiles of
// fused GEMM (0 = none/last layer). ~81KB LDS -> 2 blocks/CU.
// ---------------------------------------------------------------------------
template<int NC, int KK, int MT, bool FIRST, bool LAST, bool ACCUM>
__global__ __launch_bounds__(1024, 8) void gcn_topk(
    const float* __restrict__ h_in,      // [G*NC,128] = x @ W
    const int* __restrict__ srcIn, const int* __restrict__ dstIn, // FIRST only
    int* ePK,                            // packed edges, remapped IN PLACE
    const float* __restrict__ bias, const float* __restrict__ p,
    const short* __restrict__ Whi, const short* __restrict__ Wlo, // next W (MT>0)
    float* __restrict__ h_out,           // [G*KK,128] next pre-acts (MT>0)
    float* __restrict__ z)               // [G,256]
{
    constexpr int GP = (MT > 0) ? MT * 16 : KK;   // gate pad
    __shared__ float h_s[NC][132];
    __shared__ float2 csr[1024];         // CSR; later readout scratch
    __shared__ int   head[NC];
    __shared__ float deg_s[NC], dis_s[NC], invd_s[NC];
    __shared__ float sc[128];
    __shared__ int   id[128];
    __shared__ float gate[GP];
    __shared__ float b_s[128], p_s[128];
    __shared__ int   remap_l[NC];
    __shared__ float pnorm;

    const int g = blockIdx.x, tid = threadIdx.x, lane = tid & 63;
    const int f4 = (tid & 31) * 4;
    const int grp = tid >> 5;
    const float NINF = -__builtin_inff();
    constexpr int NIT4 = (NC + 31) / 32;

    // ---- edge in registers (slot g*1024+tid owned by this thread)
    int es_r, ed_r; bool live;
    {
        int eg = g * 1024 + tid;
        if (FIRST) { es_r = srcIn[eg] & 127; ed_r = dstIn[eg] & 127; live = true; }
        else       { int pk = ePK[eg]; es_r = pk & 127; ed_r = (pk >> 7) & 127; live = (pk >> 14) != 0; }
    }

    // ---- stage h tile (float4, stride-132 rows) + init
    {
        const float* hp = h_in + (long)g * NC * 128;
        for (int i = tid; i < NC * 32; i += 1024) {
            int row = i >> 5, c4 = (i & 31) << 2;
            *(float4*)&h_s[row][c4] = *(const float4*)&hp[row * 128 + c4];
        }
    }
    if (tid < 128) { b_s[tid] = bias[tid]; p_s[tid] = p[tid]; }
    for (int i = tid; i < NC; i += 1024) { deg_s[i] = 1.f; head[i] = 0; }
    __syncthreads();

    // ---- ||p|| (wave0) + degree/count histograms
    if (tid < 64) {
        float s = p_s[tid] * p_s[tid] + p_s[tid + 64] * p_s[tid + 64];
#pragma unroll
        for (int o = 32; o; o >>= 1) s += __shfl_xor(s, o, 64);
        if (tid == 0) pnorm = sqrtf(s);
    }
    if (live) {
        atomicAdd(&deg_s[ed_r], 1.0f);
        atomicAdd(&head[ed_r], 1);
    }
    __syncthreads();

    for (int i = tid; i < NC; i += 1024) {
        float d = deg_s[i];
        dis_s[i] = 1.0f / sqrtf(d);
        invd_s[i] = 1.0f / d;
    }
    // ---- exclusive scan of counts -> head (wave0)
    if (tid < 64) {
        int c0 = head[tid];
        int c1 = (tid + 64 < NC) ? head[tid + 64] : 0;
        int s0 = c0, s1 = c1;
#pragma unroll
        for (int o = 1; o < 64; o <<= 1) { int t = __shfl_up(s0, o, 64); if (lane >= o) s0 += t; }
        int tot0 = __shfl(s0, 63, 64);
#pragma unroll
        for (int o = 1; o < 64; o <<= 1) { int t = __shfl_up(s1, o, 64); if (lane >= o) s1 += t; }
        s1 += tot0;
        head[tid] = s0 - c0;
        if (tid + 64 < NC) head[tid + 64] = s1 - c1;
    }
    __syncthreads();

    // ---- CSR place (head becomes per-node END offset)
    if (live) {
        int slot = atomicAdd(&head[ed_r], 1);
        csr[slot] = make_float2(__int_as_float(es_r), dis_s[es_r] * dis_s[ed_r]);
    }
    __syncthreads();

    // ---- float4 gather-aggregate + act (regs) + full-dot score per node
    const float4 p4 = *(const float4*)&p_s[f4];
    const float4 b4 = *(const float4*)&b_s[f4];
    float4 va[NIT4];
#pragma unroll
    for (int i = 0; i < NIT4; ++i) {
        int nd = grp + i * 32;
        if ((NC & 31) == 0 || nd < NC) {
            int kb = nd ? head[nd - 1] : 0;
            int ke = head[nd];
            float4 acc = make_float4(0.f, 0.f, 0.f, 0.f);
            for (int k = kb; k < ke; ++k) {
                float2 rec = csr[k];
                const float4 hv = *(const float4*)&h_s[__float_as_int(rec.x)][f4];
                acc.x = fmaf(hv.x, rec.y, acc.x);
                acc.y = fmaf(hv.y, rec.y, acc.y);
                acc.z = fmaf(hv.z, rec.y, acc.z);
                acc.w = fmaf(hv.w, rec.y, acc.w);
            }
            const float4 h0 = *(const float4*)&h_s[nd][f4];
            const float iv = invd_s[nd];
            float4 v;
            v.x = acc.x + h0.x * iv + b4.x;
            v.y = acc.y + h0.y * iv + b4.y;
            v.z = acc.z + h0.z * iv + b4.z;
            v.w = acc.w + h0.w * iv + b4.w;
            v.x = v.x >= 0.f ? v.x : NEGS * v.x;
            v.y = v.y >= 0.f ? v.y : NEGS * v.y;
            v.z = v.z >= 0.f ? v.z : NEGS * v.z;
            v.w = v.w >= 0.f ? v.w : NEGS * v.w;
            va[i] = v;
            float ps = v.x * p4.x + v.y * p4.y + v.z * p4.z + v.w * p4.w;
            ps += __shfl_xor(ps, 16, 64);
            ps += __shfl_xor(ps, 8, 64);
            ps += __shfl_xor(ps, 4, 64);
            ps += __shfl_xor(ps, 2, 64);
            ps += __shfl_xor(ps, 1, 64);
            if ((tid & 31) == 0) sc[nd] = ps;
        }
    }
    __syncthreads();

    // ---- overwrite h_s with activated values
#pragma unroll
    for (int i = 0; i < NIT4; ++i) {
        int nd = grp + i * 32;
        if ((NC & 31) == 0 || nd < NC) *(float4*)&h_s[nd][f4] = va[i];
    }
    __syncthreads();

    // ---- finalize scores
    if (tid < 128) {
        if (tid < NC) { sc[tid] = sc[tid] / pnorm; id[tid] = tid; }
        else          { sc[tid] = NINF; id[tid] = 0x7fffffff; }
    }
    __syncthreads();

    // ---- bitonic sort (128) on wave 0, lockstep
    if (tid < 64) {
        for (int size = 2; size <= 128; size <<= 1) {
            for (int stride = size >> 1; stride > 0; stride >>= 1) {
                int i = 2 * stride * (tid / stride) + (tid % stride);
                int j = i + stride;
                float si_ = sc[i], sj_ = sc[j];
                int ii = id[i], ij = id[j];
                bool iFirst = (si_ > sj_) || (si_ == sj_ && ii < ij);
                bool descRegion = ((i & size) == 0);
                bool doSwap = descRegion ? !iFirst : iFirst;
                if (doSwap) { sc[i] = sj_; sc[j] = si_; id[i] = ij; id[j] = ii; }
                __asm__ volatile("" ::: "memory");
            }
        }
    }
    __syncthreads();

    // ---- gates (0-padded to GP) + remap table
    for (int j = tid; j < GP; j += 1024) gate[j] = (j < KK) ? tanhf(sc[j]) : 0.f;
    if constexpr (!LAST) {
        for (int i = tid; i < NC; i += 1024) remap_l[i] = -1;
    }
    __syncthreads();
    if constexpr (!LAST) {
        for (int j = tid; j < KK; j += 1024) remap_l[id[j]] = j;
    }
    __syncthreads();

    // ---- in-place packed edge remap
    if constexpr (!LAST) {
        int s2 = remap_l[es_r], d2 = remap_l[ed_r];
        bool ok = (s2 >= 0) && (d2 >= 0);
        int lv = (live && ok) ? 1 : 0;
        ePK[g * 1024 + tid] = (ok ? s2 : 0) | ((ok ? d2 : 0) << 7) | (lv << 14);
    }

    // ---- FUSED next-layer GEMM: h_out = (h_s[id[j]]*gate[j]) @ W  (K=128)
    if constexpr (MT > 0) {
        const int w = tid >> 6;
        const int mt = w & 7, ntg = w >> 3;
        if (mt < MT) {
            const int lm = lane & 15, lk = (lane >> 4) * 8;
            const int j0 = mt * 16 + lm;
            const int srow = id[j0];        // j0 < MT*16 <= NC, always valid
            const float gt = gate[j0];      // 0 for j0 >= KK
            const f32x4 zz = {0.f, 0.f, 0.f, 0.f};
            f32x4 acc[4] = {zz, zz, zz, zz};
#pragma unroll
            for (int ks = 0; ks < 4; ++ks) {
                const int k0 = ks * 32 + lk;
                float av[8];
                *(float4*)&av[0] = *(const float4*)&h_s[srow][k0];
                *(float4*)&av[4] = *(const float4*)&h_s[srow][k0 + 4];
                bf16x8 ah, al;
#pragma unroll
                for (int jj = 0; jj < 8; ++jj) {
                    short h_, l_; split2(av[jj] * gt, h_, l_);
                    ah[jj] = h_; al[jj] = l_;
                }
#pragma unroll
                for (int nt = 0; nt < 4; ++nt) {
                    const int ncol = (ntg * 4 + nt) * 16 + lm;
                    bf16x8 bh = *(const bf16x8*)&Whi[(long)ncol * 128 + k0];
                    bf16x8 bl = *(const bf16x8*)&Wlo[(long)ncol * 128 + k0];
                    acc[nt] = __builtin_amdgcn_mfma_f32_16x16x32_bf16(ah, bh, acc[nt], 0, 0, 0);
                    acc[nt] = __builtin_amdgcn_mfma_f32_16x16x32_bf16(ah, bl, acc[nt], 0, 0, 0);
                    acc[nt] = __builtin_amdgcn_mfma_f32_16x16x32_bf16(al, bh, acc[nt], 0, 0, 0);
                }
            }
            const int r0 = mt * 16 + (lane >> 4) * 4;
#pragma unroll
            for (int nt = 0; nt < 4; ++nt) {
                const int col = (ntg * 4 + nt) * 16 + lm;
#pragma unroll
                for (int r = 0; r < 4; ++r) {
                    const int j = r0 + r;
                    if (j < KK) h_out[((long)g * KK + j) * 128 + col] = acc[nt][r];
                }
            }
        }
    }

    // ---- readout: max & mean over gated pooled rows (csr as scratch, 2-pass)
    float* csrF = (float*)&csr[0];       // 2048 floats = 16 rows x 128
    {
        const int jj = tid >> 5;
        float4 rmx = make_float4(NINF, NINF, NINF, NINF);
        float4 rsm = make_float4(0.f, 0.f, 0.f, 0.f);
        for (int j = jj; j < KK; j += 32) {
            const float gt = gate[j];
            const float4 hv = *(const float4*)&h_s[id[j]][f4];
            float4 v;
            v.x = hv.x * gt; v.y = hv.y * gt; v.z = hv.z * gt; v.w = hv.w * gt;
            rmx.x = fmaxf(rmx.x, v.x); rmx.y = fmaxf(rmx.y, v.y);
            rmx.z = fmaxf(rmx.z, v.z); rmx.w = fmaxf(rmx.w, v.w);
            rsm.x += v.x; rsm.y += v.y; rsm.z += v.z; rsm.w += v.w;
        }
        rmx.x = fmaxf(rmx.x, __shfl_xor(rmx.x, 32, 64));
        rmx.y = fmaxf(rmx.y, __shfl_xor(rmx.y, 32, 64));
        rmx.z = fmaxf(rmx.z, __shfl_xor(rmx.z, 32, 64));
        rmx.w = fmaxf(rmx.w, __shfl_xor(rmx.w, 32, 64));
        rsm.x += __shfl_xor(rsm.x, 32, 64);
        rsm.y += __shfl_xor(rsm.y, 32, 64);
        rsm.z += __shfl_xor(rsm.z, 32, 64);
        rsm.w += __shfl_xor(rsm.w, 32, 64);
        __syncthreads();                 // csr free & all waves ready
        if (lane < 32) *(float4*)&csrF[(tid >> 6) * 128 + f4] = rmx;
        __syncthreads();
        float m = 0.f;
        if (tid < 128) {
            m = csrF[tid];
#pragma unroll
            for (int q = 1; q < 16; ++q) m = fmaxf(m, csrF[q * 128 + tid]);
        }
        __syncthreads();
        if (lane < 32) *(float4*)&csrF[(tid >> 6) * 128 + f4] = rsm;
        __syncthreads();
        if (tid < 128) {
            float s = csrF[tid];
#pragma unroll
            for (int q = 1; q < 16; ++q) s += csrF[q * 128 + tid];
            float mean = s / (float)KK;
            if constexpr (ACCUM) {
                z[g * 256 + tid] += m;
                z[g * 256 + 128 + tid] += mean;
            } else {
                z[g * 256 + tid] = m;
                z[g * 256 + 128 + tid] = mean;
            }
        }
    }
}

// ---------------------------------------------------------------------------
// MLP tail per row: lin2 (1024->64) + lrelu + bn2, lin3 (64->2) + bias.
// ---------------------------------------------------------------------------
__global__ __launch_bounds__(256) void mlp_tail(
    const float* __restrict__ t1,
    const float* __restrict__ W2, const float* __restrict__ b2v,
    const float* __restrict__ g2, const float* __restrict__ bb2,
    const float* __restrict__ rm2, const float* __restrict__ rv2,
    const float* __restrict__ W3, const float* __restrict__ b3v,
    float* __restrict__ out)
{
    __shared__ float t1s[1024];
    __shared__ float part[4][64];
    __shared__ float t2s[64];
    const int row = blockIdx.x, tid = threadIdx.x;

    for (int i = tid; i < 1024; i += 256) t1s[i] = t1[(long)row * 1024 + i];
    __syncthreads();

    int c = tid & 63, seg = tid >> 6;
    float s = 0.f;
    for (int k = seg * 256; k < seg * 256 + 256; ++k)
        s = fmaf(t1s[k], W2[k * 64 + c], s);
    part[seg][c] = s;
    __syncthreads();

    if (tid < 64) {
        float v = part[0][c] + part[1][c] + part[2][c] + part[3][c] + b2v[c];
        v = v >= 0.f ? v : NEGS * v;
        v = (v - rm2[c]) * (1.0f / sqrtf(rv2[c] + BNEPS)) * g2[c] + bb2[c];
        t2s[c] = v;
    }
    __syncthreads();

    if (tid < 128) {
        int cc = tid >> 6, k = tid & 63;
        float prod = t2s[k] * W3[k * 2 + cc];
#pragma unroll
        for (int o = 32; o; o >>= 1) prod += __shfl_xor(prod, o, 64);
        if (k == 0) out[row * 2 + cc] = prod + b3v[cc];
    }
}

// ---------------------------------------------------------------------------
extern "C" void kernel_launch(void* const* d_in, const int* in_sizes, int n_in,
                              void* d_out, int out_size, void* d_ws, size_t ws_size,
                              hipStream_t stream)
{
    const float* x    = (const float*)d_in[0];
    const int*   src  = (const int*)d_in[1];
    const int*   dst  = (const int*)d_in[2];
    const float* W1   = (const float*)d_in[4];
    const float* b1   = (const float*)d_in[5];
    const float* W2   = (const float*)d_in[6];
    const float* b2   = (const float*)d_in[7];
    const float* W3   = (const float*)d_in[8];
    const float* b3   = (const float*)d_in[9];
    const float* p1   = (const float*)d_in[10];
    const float* p2   = (const float*)d_in[11];
    const float* p3   = (const float*)d_in[12];
    const float* l1W  = (const float*)d_in[13];
    const float* l1b  = (const float*)d_in[14];
    const float* l2W  = (const float*)d_in[15];
    const float* l2b  = (const float*)d_in[16];
    const float* l3W  = (const float*)d_in[17];
    const float* l3b  = (const float*)d_in[18];
    const float* bn1g = (const float*)d_in[19];
    const float* bn1b = (const float*)d_in[20];
    const float* bn1rm= (const float*)d_in[21];
    const float* bn1rv= (const float*)d_in[22];
    const float* bn2g = (const float*)d_in[23];
    const float* bn2b = (const float*)d_in[24];
    const float* bn2rm= (const float*)d_in[25];
    const float* bn2rv= (const float*)d_in[26];
    float* out = (float*)d_out;

    // workspace layout (floats)
    float* ws = (float*)d_ws;
    size_t o = 0;
    float* h1 = ws + o; o += 65536L * 128;       // gemm1 out; later h3 arena
    float* h2 = ws + o; o += 52736L * 128;       // fused-out of gcn1
    float* z  = ws + o; o += 512L * 256;
    float* t1 = ws + o; o += 512L * 1024;
    int*   ePK = (int*)(ws + o); o += 524288;
    short* sp = (short*)(ws + o);
    short* h1s = sp;               // W1 hi  [128][160]
    short* l1s = h1s + 20480;
    short* h2s = l1s + 20480;      // W2 hi  [128][128]
    short* l2s = h2s + 16384;
    short* h3s = l2s + 16384;      // W3 hi
    short* l3s = h3s + 16384;
    short* h4s = l3s + 16384;      // lin1_W hi [1024][256]
    short* l4s = h4s + 262144;
    float* h3 = h1;                // reuse gemm1-out arena for layer-3 pre-acts

    // ---- precompute weight splits
    split_all<<<1232, 256, 0, stream>>>(W1, W2, W3, l1W,
        h1s, l1s, h2s, l2s, h3s, l3s, h4s, l4s);

    // ---- Layer 1 GEMM: h1 = x @ W1  (M=65536, K=133->160)
    gemm_bres<133,160,0><<<dim3(512,1), 256, 0, stream>>>(
        x, h1s, l1s, h1, 128, nullptr, nullptr, nullptr, nullptr, nullptr);

    // ---- gcn1 (+fused GEMM2 -> h2)
    gcn_topk<128,103,7,true,false,false><<<512, 1024, 0, stream>>>(
        h1, src, dst, ePK, b1, p1, h2s, l2s, h2, z);

    // ---- gcn2 (+fused GEMM3 -> h3)
    gcn_topk<103,83,6,false,false,true><<<512, 1024, 0, stream>>>(
        h2, nullptr, nullptr, ePK, b2, p2, h3s, l3s, h3, z);

    // ---- gcn3 (readout only)
    gcn_topk<83,67,0,false,true,true><<<512, 1024, 0, stream>>>(
        h3, nullptr, nullptr, ePK, b3, p3, nullptr, nullptr, nullptr, z);

    // ---- MLP head: t1 = bn1(lrelu(z @ lin1_W + b))  (M=512, N=1024, K=256)
    gemm_bres<256,256,1><<<dim3(4,8), 256, 0, stream>>>(
        z, h4s, l4s, t1, 1024, l1b, bn1g, bn1b, bn1rm, bn1rv);
    mlp_tail<<<512, 256, 0, stream>>>(
        t1, l2W, l2b, bn2g, bn2b, bn2rm, bn2rv, l3W, l3b, out);
}